// Round 6
// baseline (165.323 us; speedup 1.0000x reference)
//
#include <hip/hip_runtime.h>
#include <hip/hip_bf16.h>

using bf16 = __hip_bfloat16;
typedef __attribute__((ext_vector_type(8))) short frag_ab;   // 8 bf16
typedef __attribute__((ext_vector_type(4))) float frag_cd;   // 4 fp32

constexpr float TEMP   = 0.07f;
constexpr float INVT   = 1.0f / TEMP;                 // fixed logsumexp shift
constexpr float THRESH = 0.1f;
constexpr float EPS    = 1e-8f;
constexpr float LOG2E  = 1.4426950408889634f;
constexpr float C1     = LOG2E / TEMP;                // exp((s-1)/T) = exp2(s*C1 - C1)

constexpr int D = 128;

__device__ __forceinline__ frag_cd mfma16(frag_ab a, frag_ab b, frag_cd c) {
    return __builtin_amdgcn_mfma_f32_16x16x32_bf16(a, b, c, 0, 0, 0);
}

// ------- kernel 1: row-normalize -> bf16, diagonal dot, zero-init reduction cells -------
__global__ __launch_bounds__(256) void k1_normalize(
    const float* __restrict__ f, bf16* __restrict__ fn,
    float* __restrict__ diag, float* __restrict__ acc,
    unsigned* __restrict__ counter, int n)
{
    if (blockIdx.x == 0 && threadIdx.x == 0) { acc[0] = 0.f; counter[0] = 0u; }
    const int row  = blockIdx.x * 4 + (threadIdx.x >> 6);
    const int lane = threadIdx.x & 63;
    float2 v = ((const float2*)(f + (size_t)row * D))[lane];
    float ss = v.x * v.x + v.y * v.y;
    #pragma unroll
    for (int m = 32; m >= 1; m >>= 1) ss += __shfl_xor(ss, m, 64);
    const float inv = 1.0f / fmaxf(sqrtf(ss), EPS);
    __hip_bfloat162 o;
    o.x = __float2bfloat16(v.x * inv);
    o.y = __float2bfloat16(v.y * inv);
    ((__hip_bfloat162*)(fn + (size_t)row * D))[lane] = o;
    // diagonal raw dot of the bf16-rounded row (matches MFMA s_ii to ~1e-6)
    const float a = __bfloat162float(o.x), b = __bfloat162float(o.y);
    float p = a * a + b * b;
    #pragma unroll
    for (int m = 32; m >= 1; m >>= 1) p += __shfl_xor(p, m, 64);
    if (lane == 0) diag[row] = p;
}

// ---------------- kernel 2: symmetric fused sim + masked reductions ----------------
// One block per upper-triangle tile-pair (I<=J), 128x128. sim/e/mask are symmetric,
// so each element serves row i AND col j: half the MFMA/LDS/exp of the full sweep.
// Partials part[K][i]: block (I,J) writes rows -> [J][tile I], cols -> [I][tile J];
// exactly one writer per cell (diagonal blocks emit rows only), no atomics/zero-init.
// B tile staged ONCE per block in XOR-swizzled LDS (0 conflicts, verified R4/R5);
// a single barrier — no per-tile convoy. (256,3): VGPR cap ~170.
__global__ __launch_bounds__(256, 3) void k2_sym(
    const bf16* __restrict__ fn, const float* __restrict__ lab,
    float* __restrict__ se_p, float* __restrict__ sp_p,
    float* __restrict__ cnt_p, int n)
{
    __shared__ bf16  colbuf[128 * D];      // 32 KB, swizzled
    __shared__ float lab_c[128];
    __shared__ float colred[3][4][128];    // 6 KB cross-wave col-reduction scratch

    const int tid  = threadIdx.x;
    const int wave = tid >> 6;
    const int lane = tid & 63;
    const int quad = lane >> 4;
    const int l15  = lane & 15;
    const int nt   = n >> 7;               // 64 tiles

    // decode upper-triangle pair (I,J) from linear block id
    int t = blockIdx.x, I = 0;
    while (t >= nt - I) { t -= nt - I; ++I; }
    const int J = I + t;

    if (tid < 128) lab_c[tid] = lab[J * 128 + tid];

    const int row_base = I * 128 + wave * 32;

    // A fragments: set s covers rows row_base + s*16 + l15, k = kb*32 + quad*8 + j
    frag_ab afr[2][4];
    #pragma unroll
    for (int s = 0; s < 2; ++s) {
        const bf16* ap = fn + (size_t)(row_base + s * 16 + l15) * D + quad * 8;
        #pragma unroll
        for (int kb = 0; kb < 4; ++kb) afr[s][kb] = *(const frag_ab*)(ap + kb * 32);
    }
    float li[2][4];
    #pragma unroll
    for (int s = 0; s < 2; ++s)
        #pragma unroll
        for (int r = 0; r < 4; ++r)
            li[s][r] = lab[row_base + s * 16 + quad * 4 + r];

    // stage B tile (J*128 .. +128 cols x 128 k), two rounds of 4 to cap live regs
    const int c0    = tid >> 4;   // 0..15
    const int chunk = tid & 15;
    #pragma unroll
    for (int half = 0; half < 2; ++half) {
        frag_ab st[4];
        #pragma unroll
        for (int cc = 0; cc < 4; ++cc) {
            const int col = (half * 4 + cc) * 16 + c0;
            st[cc] = *(const frag_ab*)(fn + (size_t)(J * 128 + col) * D + chunk * 8);
        }
        #pragma unroll
        for (int cc = 0; cc < 4; ++cc) {
            const int col = (half * 4 + cc) * 16 + c0;
            *(frag_ab*)(&colbuf[(size_t)col * D + ((chunk ^ c0) * 8)]) = st[cc];
        }
    }
    __syncthreads();

    float se[2][4] = {}, sp[2][4] = {}, cnt[2][4] = {};
    float sec[8] = {}, spc[8] = {}, cnc[8] = {};

    #pragma unroll
    for (int sub = 0; sub < 8; ++sub) {
        const int c = sub * 16 + l15;          // column within tile
        frag_ab b[4];
        #pragma unroll
        for (int kb = 0; kb < 4; ++kb)
            b[kb] = *(const frag_ab*)(&colbuf[(size_t)c * D + (((quad + 4 * kb) ^ l15) * 8)]);
        frag_cd a0 = {0.f, 0.f, 0.f, 0.f}, a1 = {0.f, 0.f, 0.f, 0.f};
        #pragma unroll
        for (int kb = 0; kb < 4; ++kb) {
            a0 = mfma16(afr[0][kb], b[kb], a0);
            a1 = mfma16(afr[1][kb], b[kb], a1);
        }
        const float lj = lab_c[c];
        #pragma unroll
        for (int s = 0; s < 2; ++s) {
            const frag_cd& acc = s ? a1 : a0;
            #pragma unroll
            for (int r = 0; r < 4; ++r) {
                const float sv = acc[r];                      // raw dot (cosine)
                const float e  = __builtin_amdgcn_exp2f(__builtin_fmaf(sv, C1, -C1));
                const float pm = (fabsf(li[s][r] - lj) < THRESH) ? 1.0f : 0.0f;
                se[s][r]  += e;                               // row accums
                sp[s][r]   = __builtin_fmaf(pm, sv, sp[s][r]);
                cnt[s][r] += pm;
                sec[sub]  += e;                               // col accums (symmetry)
                spc[sub]   = __builtin_fmaf(pm, sv, spc[sub]);
                cnc[sub]  += pm;
            }
        }
    }

    // ---- row partials: reduce across the 16 lanes of each quad-group, write [J][rows] ----
    #pragma unroll
    for (int s = 0; s < 2; ++s)
        #pragma unroll
        for (int r = 0; r < 4; ++r) {
            #pragma unroll
            for (int m = 1; m < 16; m <<= 1) {
                se[s][r]  += __shfl_xor(se[s][r],  m, 64);
                sp[s][r]  += __shfl_xor(sp[s][r],  m, 64);
                cnt[s][r] += __shfl_xor(cnt[s][r], m, 64);
            }
        }
    if (l15 == 0) {
        #pragma unroll
        for (int s = 0; s < 2; ++s)
            #pragma unroll
            for (int r = 0; r < 4; ++r) {
                const int i = row_base + s * 16 + quad * 4 + r;
                se_p[(size_t)J * n + i]  = se[s][r];
                sp_p[(size_t)J * n + i]  = sp[s][r];
                cnt_p[(size_t)J * n + i] = cnt[s][r];
            }
    }

    // ---- col partials: quad-reduce (rows within wave), LDS cross-wave sum, write [I][cols] ----
    #pragma unroll
    for (int sub = 0; sub < 8; ++sub) {
        sec[sub] += __shfl_xor(sec[sub], 16, 64); sec[sub] += __shfl_xor(sec[sub], 32, 64);
        spc[sub] += __shfl_xor(spc[sub], 16, 64); spc[sub] += __shfl_xor(spc[sub], 32, 64);
        cnc[sub] += __shfl_xor(cnc[sub], 16, 64); cnc[sub] += __shfl_xor(cnc[sub], 32, 64);
    }
    if (lane < 16) {
        #pragma unroll
        for (int sub = 0; sub < 8; ++sub) {
            colred[0][wave][sub * 16 + lane] = sec[sub];
            colred[1][wave][sub * 16 + lane] = spc[sub];
            colred[2][wave][sub * 16 + lane] = cnc[sub];
        }
    }
    __syncthreads();
    if (I != J && tid < 128) {
        const float s0 = colred[0][0][tid] + colred[0][1][tid] + colred[0][2][tid] + colred[0][3][tid];
        const float s1 = colred[1][0][tid] + colred[1][1][tid] + colred[1][2][tid] + colred[1][3][tid];
        const float s2 = colred[2][0][tid] + colred[2][1][tid] + colred[2][2][tid] + colred[2][3][tid];
        const int j = J * 128 + tid;
        se_p[(size_t)I * n + j]  = s0;
        sp_p[(size_t)I * n + j]  = s1;
        cnt_p[(size_t)I * n + j] = s2;
    }
}

// ------- kernel 3: per-row finalize + grid reduction (last-block pattern) -------
__global__ __launch_bounds__(256) void k3_finalize(
    const float* __restrict__ diag, const float* __restrict__ se_p,
    const float* __restrict__ sp_p, const float* __restrict__ cnt_p,
    float* __restrict__ acc, unsigned* __restrict__ counter,
    float* __restrict__ out, int n)
{
    const int row = blockIdx.x * 256 + threadIdx.x;
    const int nt  = n >> 7;
    float se = 0.f, sp = 0.f, cnt = 0.f;
    for (int K = 0; K < nt; ++K) {
        se  += se_p[(size_t)K * n + row];
        sp  += sp_p[(size_t)K * n + row];
        cnt += cnt_p[(size_t)K * n + row];
    }
    const float s_ii = diag[row];
    se  -= __builtin_amdgcn_exp2f(__builtin_fmaf(s_ii, C1, -C1));
    sp  -= s_ii;
    cnt -= 1.0f;
    float loss = INVT + __logf(se) - (sp * INVT) / fmaxf(cnt, 1.0f);

    // block reduce
    #pragma unroll
    for (int m = 32; m >= 1; m >>= 1) loss += __shfl_xor(loss, m, 64);
    __shared__ float wsum[4];
    if ((threadIdx.x & 63) == 0) wsum[threadIdx.x >> 6] = loss;
    __syncthreads();
    if (threadIdx.x == 0) {
        const float bs = wsum[0] + wsum[1] + wsum[2] + wsum[3];
        atomicAdd(acc, bs);
        __threadfence();
        const unsigned old = atomicAdd(counter, 1u);
        if (old == gridDim.x - 1) {
            const float total = atomicAdd(acc, 0.0f);  // atomic load, same-address order
            out[0] = total / (float)n;
        }
    }
}

extern "C" void kernel_launch(void* const* d_in, const int* in_sizes, int n_in,
                              void* d_out, int out_size, void* d_ws, size_t ws_size,
                              hipStream_t stream) {
    const float* feat = (const float*)d_in[0];
    const float* lab  = (const float*)d_in[1];
    const int n = in_sizes[1];              // 8192
    float* out = (float*)d_out;
    const int nt = n >> 7;                  // 64 row-tiles

    // ws: fn (n*D bf16 = 2MB) | diag | se_p | sp_p | cnt_p (each nt*n f32 = 2MB) | acc | counter
    char* ws = (char*)d_ws;
    bf16* fn = (bf16*)ws;
    size_t off = (size_t)n * D * sizeof(bf16);
    float* diag  = (float*)(ws + off); off += (size_t)n * sizeof(float);
    float* se_p  = (float*)(ws + off); off += (size_t)nt * n * sizeof(float);
    float* sp_p  = (float*)(ws + off); off += (size_t)nt * n * sizeof(float);
    float* cnt_p = (float*)(ws + off); off += (size_t)nt * n * sizeof(float);
    float* acc   = (float*)(ws + off); off += sizeof(float);
    unsigned* counter = (unsigned*)(ws + off);

    k1_normalize<<<n / 4, 256, 0, stream>>>(feat, fn, diag, acc, counter, n);
    const int npairs = nt * (nt + 1) / 2;   // 2080
    k2_sym<<<npairs, 256, 0, stream>>>(fn, lab, se_p, sp_p, cnt_p, n);
    k3_finalize<<<n / 256, 256, 0, stream>>>(diag, se_p, sp_p, cnt_p, acc, counter, out, n);
}

// Round 7
// 148.930 us; speedup vs baseline: 1.1101x; 1.1101x over previous
//
#include <hip/hip_runtime.h>
#include <hip/hip_bf16.h>

using bf16 = __hip_bfloat16;
typedef __attribute__((ext_vector_type(8))) short frag_ab;   // 8 bf16
typedef __attribute__((ext_vector_type(4))) float frag_cd;   // 4 fp32

constexpr float TEMP   = 0.07f;
constexpr float INVT   = 1.0f / TEMP;                 // fixed logsumexp shift
constexpr float THRESH = 0.1f;
constexpr float EPS    = 1e-8f;
constexpr float LOG2E  = 1.4426950408889634f;
constexpr float C1     = LOG2E / TEMP;                // exp((s-1)/T) = exp2(s*C1 - C1)

constexpr int D = 128;

__device__ __forceinline__ frag_cd mfma16(frag_ab a, frag_ab b, frag_cd c) {
    return __builtin_amdgcn_mfma_f32_16x16x32_bf16(a, b, c, 0, 0, 0);
}

// ------- kernel 1: row-normalize -> bf16, diagonal dot, zero-init reduction cells -------
__global__ __launch_bounds__(256) void k1_normalize(
    const float* __restrict__ f, bf16* __restrict__ fn,
    float* __restrict__ diag, float* __restrict__ acc,
    unsigned* __restrict__ counter, int n)
{
    if (blockIdx.x == 0 && threadIdx.x == 0) { acc[0] = 0.f; counter[0] = 0u; }
    const int row  = blockIdx.x * 4 + (threadIdx.x >> 6);
    const int lane = threadIdx.x & 63;
    float2 v = ((const float2*)(f + (size_t)row * D))[lane];
    float ss = v.x * v.x + v.y * v.y;
    #pragma unroll
    for (int m = 32; m >= 1; m >>= 1) ss += __shfl_xor(ss, m, 64);
    const float inv = 1.0f / fmaxf(sqrtf(ss), EPS);
    __hip_bfloat162 o;
    o.x = __float2bfloat16(v.x * inv);
    o.y = __float2bfloat16(v.y * inv);
    ((__hip_bfloat162*)(fn + (size_t)row * D))[lane] = o;
    // diagonal raw dot of the bf16-rounded row (matches MFMA s_ii to ~1e-6)
    const float a = __bfloat162float(o.x), b = __bfloat162float(o.y);
    float p = a * a + b * b;
    #pragma unroll
    for (int m = 32; m >= 1; m >>= 1) p += __shfl_xor(p, m, 64);
    if (lane == 0) diag[row] = p;
}

// ---------------- kernel 2: symmetric fused sim + masked reductions ----------------
// One block per upper-triangle tile-pair (I<=J), 128x128; each element serves row i
// AND col j (sim/e/mask symmetric) -> half the MFMA/LDS/exp of the full sweep.
// R6 POST-MORTEM: 24 persistent col-accumulator VGPRs spilled (208 MB scratch
// writes). Fix: each sub's 16 cols are DISJOINT, so after the 2-shfl quad-reduce
// the finished col partials go straight to LDS (plain store, no persistent regs).
// Partials part[K][i]: rows -> [J][tile I], cols -> [I][tile J]; one writer per
// cell (diagonal blocks emit rows only), no atomics, no zero-init.
__global__ __launch_bounds__(256, 3) void k2_sym(
    const bf16* __restrict__ fn, const float* __restrict__ lab,
    float* __restrict__ se_p, float* __restrict__ sp_p,
    float* __restrict__ cnt_p, int n)
{
    __shared__ bf16  colbuf[128 * D];      // 32 KB, XOR-swizzled (0 conflicts, R4/R5)
    __shared__ float lab_c[128];
    __shared__ float colred[3][4][128];    // 6 KB cross-wave col-reduction scratch

    const int tid  = threadIdx.x;
    const int wave = tid >> 6;
    const int lane = tid & 63;
    const int quad = lane >> 4;
    const int l15  = lane & 15;
    const int nt   = n >> 7;               // 64 tiles

    // decode upper-triangle pair (I,J) from linear block id
    int t = blockIdx.x, I = 0;
    while (t >= nt - I) { t -= nt - I; ++I; }
    const int J = I + t;

    if (tid < 128) lab_c[tid] = lab[J * 128 + tid];

    const int row_base = I * 128 + wave * 32;

    // A fragments: set s covers rows row_base + s*16 + l15, k = kb*32 + quad*8 + j
    frag_ab afr[2][4];
    #pragma unroll
    for (int s = 0; s < 2; ++s) {
        const bf16* ap = fn + (size_t)(row_base + s * 16 + l15) * D + quad * 8;
        #pragma unroll
        for (int kb = 0; kb < 4; ++kb) afr[s][kb] = *(const frag_ab*)(ap + kb * 32);
    }
    float li[2][4];
    #pragma unroll
    for (int s = 0; s < 2; ++s)
        #pragma unroll
        for (int r = 0; r < 4; ++r)
            li[s][r] = lab[row_base + s * 16 + quad * 4 + r];

    // stage B tile (J*128 .. +128 cols x 128 k), two rounds of 4 to cap live regs
    const int c0    = tid >> 4;   // 0..15
    const int chunk = tid & 15;
    #pragma unroll
    for (int half = 0; half < 2; ++half) {
        frag_ab st[4];
        #pragma unroll
        for (int cc = 0; cc < 4; ++cc) {
            const int col = (half * 4 + cc) * 16 + c0;
            st[cc] = *(const frag_ab*)(fn + (size_t)(J * 128 + col) * D + chunk * 8);
        }
        #pragma unroll
        for (int cc = 0; cc < 4; ++cc) {
            const int col = (half * 4 + cc) * 16 + c0;
            *(frag_ab*)(&colbuf[(size_t)col * D + ((chunk ^ c0) * 8)]) = st[cc];
        }
    }
    __syncthreads();

    float se[2][4] = {}, sp[2][4] = {}, cnt[2][4] = {};

    #pragma unroll
    for (int sub = 0; sub < 8; ++sub) {
        const int c = sub * 16 + l15;          // column within tile
        frag_ab b[4];
        #pragma unroll
        for (int kb = 0; kb < 4; ++kb)
            b[kb] = *(const frag_ab*)(&colbuf[(size_t)c * D + (((quad + 4 * kb) ^ l15) * 8)]);
        frag_cd a0 = {0.f, 0.f, 0.f, 0.f}, a1 = {0.f, 0.f, 0.f, 0.f};
        #pragma unroll
        for (int kb = 0; kb < 4; ++kb) {
            a0 = mfma16(afr[0][kb], b[kb], a0);
            a1 = mfma16(afr[1][kb], b[kb], a1);
        }
        const float lj = lab_c[c];
        float sec = 0.f, spc = 0.f, cnc = 0.f;   // this sub's col partials (transient)
        #pragma unroll
        for (int s = 0; s < 2; ++s) {
            const frag_cd& acc = s ? a1 : a0;
            #pragma unroll
            for (int r = 0; r < 4; ++r) {
                const float sv = acc[r];                      // raw dot (cosine)
                const float e  = __builtin_amdgcn_exp2f(__builtin_fmaf(sv, C1, -C1));
                const float pm = (fabsf(li[s][r] - lj) < THRESH) ? 1.0f : 0.0f;
                se[s][r]  += e;                               // row accums (registers)
                sp[s][r]   = __builtin_fmaf(pm, sv, sp[s][r]);
                cnt[s][r] += pm;
                sec += e;                                     // col accums (transient)
                spc  = __builtin_fmaf(pm, sv, spc);
                cnc += pm;
            }
        }
        // quad-reduce (sums the wave's 32 rows) then straight to LDS — no live regs kept
        sec += __shfl_xor(sec, 16, 64); sec += __shfl_xor(sec, 32, 64);
        spc += __shfl_xor(spc, 16, 64); spc += __shfl_xor(spc, 32, 64);
        cnc += __shfl_xor(cnc, 16, 64); cnc += __shfl_xor(cnc, 32, 64);
        if (lane < 16) {
            colred[0][wave][c] = sec;
            colred[1][wave][c] = spc;
            colred[2][wave][c] = cnc;
        }
    }

    // ---- row partials: reduce across the 16 lanes of each quad-group, write [J][rows] ----
    #pragma unroll
    for (int s = 0; s < 2; ++s)
        #pragma unroll
        for (int r = 0; r < 4; ++r) {
            #pragma unroll
            for (int m = 1; m < 16; m <<= 1) {
                se[s][r]  += __shfl_xor(se[s][r],  m, 64);
                sp[s][r]  += __shfl_xor(sp[s][r],  m, 64);
                cnt[s][r] += __shfl_xor(cnt[s][r], m, 64);
            }
        }
    if (l15 == 0) {
        #pragma unroll
        for (int s = 0; s < 2; ++s)
            #pragma unroll
            for (int r = 0; r < 4; ++r) {
                const int i = row_base + s * 16 + quad * 4 + r;
                se_p[(size_t)J * n + i]  = se[s][r];
                sp_p[(size_t)J * n + i]  = sp[s][r];
                cnt_p[(size_t)J * n + i] = cnt[s][r];
            }
    }

    // ---- col partials: cross-wave sum of the 4 LDS slots, write [I][cols] ----
    __syncthreads();
    if (I != J && tid < 128) {
        const float s0 = colred[0][0][tid] + colred[0][1][tid] + colred[0][2][tid] + colred[0][3][tid];
        const float s1 = colred[1][0][tid] + colred[1][1][tid] + colred[1][2][tid] + colred[1][3][tid];
        const float s2 = colred[2][0][tid] + colred[2][1][tid] + colred[2][2][tid] + colred[2][3][tid];
        const int j = J * 128 + tid;
        se_p[(size_t)I * n + j]  = s0;
        sp_p[(size_t)I * n + j]  = s1;
        cnt_p[(size_t)I * n + j] = s2;
    }
}

// ------- kernel 3: per-row finalize + grid reduction (last-block pattern) -------
__global__ __launch_bounds__(256) void k3_finalize(
    const float* __restrict__ diag, const float* __restrict__ se_p,
    const float* __restrict__ sp_p, const float* __restrict__ cnt_p,
    float* __restrict__ acc, unsigned* __restrict__ counter,
    float* __restrict__ out, int n)
{
    const int row = blockIdx.x * 256 + threadIdx.x;
    const int nt  = n >> 7;
    float se = 0.f, sp = 0.f, cnt = 0.f;
    for (int K = 0; K < nt; ++K) {
        se  += se_p[(size_t)K * n + row];
        sp  += sp_p[(size_t)K * n + row];
        cnt += cnt_p[(size_t)K * n + row];
    }
    const float s_ii = diag[row];
    se  -= __builtin_amdgcn_exp2f(__builtin_fmaf(s_ii, C1, -C1));
    sp  -= s_ii;
    cnt -= 1.0f;
    float loss = INVT + __logf(se) - (sp * INVT) / fmaxf(cnt, 1.0f);

    // block reduce
    #pragma unroll
    for (int m = 32; m >= 1; m >>= 1) loss += __shfl_xor(loss, m, 64);
    __shared__ float wsum[4];
    if ((threadIdx.x & 63) == 0) wsum[threadIdx.x >> 6] = loss;
    __syncthreads();
    if (threadIdx.x == 0) {
        const float bs = wsum[0] + wsum[1] + wsum[2] + wsum[3];
        atomicAdd(acc, bs);
        __threadfence();
        const unsigned old = atomicAdd(counter, 1u);
        if (old == gridDim.x - 1) {
            const float total = atomicAdd(acc, 0.0f);  // atomic load, same-address order
            out[0] = total / (float)n;
        }
    }
}

extern "C" void kernel_launch(void* const* d_in, const int* in_sizes, int n_in,
                              void* d_out, int out_size, void* d_ws, size_t ws_size,
                              hipStream_t stream) {
    const float* feat = (const float*)d_in[0];
    const float* lab  = (const float*)d_in[1];
    const int n = in_sizes[1];              // 8192
    float* out = (float*)d_out;
    const int nt = n >> 7;                  // 64 row-tiles

    // ws: fn (n*D bf16 = 2MB) | diag | se_p | sp_p | cnt_p (each nt*n f32 = 2MB) | acc | counter
    char* ws = (char*)d_ws;
    bf16* fn = (bf16*)ws;
    size_t off = (size_t)n * D * sizeof(bf16);
    float* diag  = (float*)(ws + off); off += (size_t)n * sizeof(float);
    float* se_p  = (float*)(ws + off); off += (size_t)nt * n * sizeof(float);
    float* sp_p  = (float*)(ws + off); off += (size_t)nt * n * sizeof(float);
    float* cnt_p = (float*)(ws + off); off += (size_t)nt * n * sizeof(float);
    float* acc   = (float*)(ws + off); off += sizeof(float);
    unsigned* counter = (unsigned*)(ws + off);

    k1_normalize<<<n / 4, 256, 0, stream>>>(feat, fn, diag, acc, counter, n);
    const int npairs = nt * (nt + 1) / 2;   // 2080
    k2_sym<<<npairs, 256, 0, stream>>>(fn, lab, se_p, sp_p, cnt_p, n);
    k3_finalize<<<n / 256, 256, 0, stream>>>(diag, se_p, sp_p, cnt_p, acc, counter, out, n);
}

// Round 8
// 111.874 us; speedup vs baseline: 1.4778x; 1.3312x over previous
//
#include <hip/hip_runtime.h>
#include <hip/hip_bf16.h>

using bf16 = __hip_bfloat16;
typedef __attribute__((ext_vector_type(8))) short frag_ab;   // 8 bf16
typedef __attribute__((ext_vector_type(4))) float frag_cd;   // 4 fp32

constexpr float TEMP   = 0.07f;
constexpr float INVT   = 1.0f / TEMP;                 // fixed logsumexp shift
constexpr float THRESH = 0.1f;
constexpr float EPS    = 1e-8f;
constexpr float LOG2E  = 1.4426950408889634f;
constexpr float C1     = LOG2E / TEMP;                // exp((s-1)/T) = exp2(s*C1 - C1)

constexpr int D = 128;

__device__ __forceinline__ frag_cd mfma16(frag_ab a, frag_ab b, frag_cd c) {
    return __builtin_amdgcn_mfma_f32_16x16x32_bf16(a, b, c, 0, 0, 0);
}

// ------- kernel 1: row-normalize -> bf16, diagonal dot, zero-init reduction cells -------
__global__ __launch_bounds__(256) void k1_normalize(
    const float* __restrict__ f, bf16* __restrict__ fn,
    float* __restrict__ diag, float* __restrict__ acc,
    unsigned* __restrict__ counter, int n)
{
    if (blockIdx.x == 0 && threadIdx.x == 0) { acc[0] = 0.f; counter[0] = 0u; }
    const int row  = blockIdx.x * 4 + (threadIdx.x >> 6);
    const int lane = threadIdx.x & 63;
    float2 v = ((const float2*)(f + (size_t)row * D))[lane];
    float ss = v.x * v.x + v.y * v.y;
    #pragma unroll
    for (int m = 32; m >= 1; m >>= 1) ss += __shfl_xor(ss, m, 64);
    const float inv = 1.0f / fmaxf(sqrtf(ss), EPS);
    __hip_bfloat162 o;
    o.x = __float2bfloat16(v.x * inv);
    o.y = __float2bfloat16(v.y * inv);
    ((__hip_bfloat162*)(fn + (size_t)row * D))[lane] = o;
    // diagonal raw dot of the bf16-rounded row (matches MFMA s_ii to ~1e-6)
    const float a = __bfloat162float(o.x), b = __bfloat162float(o.y);
    float p = a * a + b * b;
    #pragma unroll
    for (int m = 32; m >= 1; m >>= 1) p += __shfl_xor(p, m, 64);
    if (lane == 0) diag[row] = p;
}

// ---------------- kernel 2: symmetric fused sim + masked reductions ----------------
// One block per upper-triangle tile-pair (I<=J), 128x128; each element serves row i
// AND col j (sim/e/mask symmetric) -> half the MFMA/LDS/exp of the full sweep.
// R6/R7 POST-MORTEM: with the 8-sub loop fully unrolled, the scheduler interleaves
// all subs (hoists 8x16 ds_read b-regs, keeps 8 col-partial chains live) -> spill
// (208 MB -> 154 MB scratch writes). FIX: #pragma unroll 1 on the sub loop bounds
// the live set to one sub (~110 regs < 170 cap). We're VALU-bound; losing
// cross-sub MFMA pipelining is fine.
__global__ __launch_bounds__(256, 3) void k2_sym(
    const bf16* __restrict__ fn, const float* __restrict__ lab,
    float* __restrict__ se_p, float* __restrict__ sp_p,
    float* __restrict__ cnt_p, int n)
{
    __shared__ bf16  colbuf[128 * D];      // 32 KB, XOR-swizzled (0 conflicts, R4/R5)
    __shared__ float lab_c[128];
    __shared__ float colred[3][4][128];    // 6 KB cross-wave col-reduction scratch

    const int tid  = threadIdx.x;
    const int wave = tid >> 6;
    const int lane = tid & 63;
    const int quad = lane >> 4;
    const int l15  = lane & 15;
    const int nt   = n >> 7;               // 64 tiles

    // decode upper-triangle pair (I,J) from linear block id
    int t = blockIdx.x, I = 0;
    while (t >= nt - I) { t -= nt - I; ++I; }
    const int J = I + t;

    if (tid < 128) lab_c[tid] = lab[J * 128 + tid];

    const int row_base = I * 128 + wave * 32;

    // A fragments: set s covers rows row_base + s*16 + l15, k = kb*32 + quad*8 + j
    frag_ab afr[2][4];
    #pragma unroll
    for (int s = 0; s < 2; ++s) {
        const bf16* ap = fn + (size_t)(row_base + s * 16 + l15) * D + quad * 8;
        #pragma unroll
        for (int kb = 0; kb < 4; ++kb) afr[s][kb] = *(const frag_ab*)(ap + kb * 32);
    }
    float li[2][4];
    #pragma unroll
    for (int s = 0; s < 2; ++s)
        #pragma unroll
        for (int r = 0; r < 4; ++r)
            li[s][r] = lab[row_base + s * 16 + quad * 4 + r];

    // stage B tile (J*128 .. +128 cols x 128 k), two rounds of 4 to cap live regs
    const int c0    = tid >> 4;   // 0..15
    const int chunk = tid & 15;
    #pragma unroll
    for (int half = 0; half < 2; ++half) {
        frag_ab st[4];
        #pragma unroll
        for (int cc = 0; cc < 4; ++cc) {
            const int col = (half * 4 + cc) * 16 + c0;
            st[cc] = *(const frag_ab*)(fn + (size_t)(J * 128 + col) * D + chunk * 8);
        }
        #pragma unroll
        for (int cc = 0; cc < 4; ++cc) {
            const int col = (half * 4 + cc) * 16 + c0;
            *(frag_ab*)(&colbuf[(size_t)col * D + ((chunk ^ c0) * 8)]) = st[cc];
        }
    }
    __syncthreads();

    float se[2][4] = {}, sp[2][4] = {}, cnt[2][4] = {};

    #pragma unroll 1   // KEEP SEQUENTIAL — full unroll recreates the R6/R7 spill
    for (int sub = 0; sub < 8; ++sub) {
        const int c = sub * 16 + l15;          // column within tile
        frag_ab b[4];
        #pragma unroll
        for (int kb = 0; kb < 4; ++kb)
            b[kb] = *(const frag_ab*)(&colbuf[(size_t)c * D + (((quad + 4 * kb) ^ l15) * 8)]);
        frag_cd a0 = {0.f, 0.f, 0.f, 0.f}, a1 = {0.f, 0.f, 0.f, 0.f};
        #pragma unroll
        for (int kb = 0; kb < 4; ++kb) {
            a0 = mfma16(afr[0][kb], b[kb], a0);
            a1 = mfma16(afr[1][kb], b[kb], a1);
        }
        const float lj = lab_c[c];
        float sec = 0.f, spc = 0.f, cnc = 0.f;   // this sub's col partials (transient)
        #pragma unroll
        for (int s = 0; s < 2; ++s) {
            const frag_cd& acc = s ? a1 : a0;
            #pragma unroll
            for (int r = 0; r < 4; ++r) {
                const float sv = acc[r];                      // raw dot (cosine)
                const float e  = __builtin_amdgcn_exp2f(__builtin_fmaf(sv, C1, -C1));
                const float pm = (fabsf(li[s][r] - lj) < THRESH) ? 1.0f : 0.0f;
                se[s][r]  += e;                               // row accums (registers)
                sp[s][r]   = __builtin_fmaf(pm, sv, sp[s][r]);
                cnt[s][r] += pm;
                sec += e;                                     // col accums (transient)
                spc  = __builtin_fmaf(pm, sv, spc);
                cnc += pm;
            }
        }
        // quad-reduce (sums the wave's 32 rows) then straight to LDS — nothing stays live
        sec += __shfl_xor(sec, 16, 64); sec += __shfl_xor(sec, 32, 64);
        spc += __shfl_xor(spc, 16, 64); spc += __shfl_xor(spc, 32, 64);
        cnc += __shfl_xor(cnc, 16, 64); cnc += __shfl_xor(cnc, 32, 64);
        if (lane < 16) {
            colred[0][wave][c] = sec;
            colred[1][wave][c] = spc;
            colred[2][wave][c] = cnc;
        }
    }

    // ---- row partials: reduce across the 16 lanes of each quad-group, write [J][rows] ----
    #pragma unroll
    for (int s = 0; s < 2; ++s)
        #pragma unroll
        for (int r = 0; r < 4; ++r) {
            #pragma unroll
            for (int m = 1; m < 16; m <<= 1) {
                se[s][r]  += __shfl_xor(se[s][r],  m, 64);
                sp[s][r]  += __shfl_xor(sp[s][r],  m, 64);
                cnt[s][r] += __shfl_xor(cnt[s][r], m, 64);
            }
        }
    if (l15 == 0) {
        #pragma unroll
        for (int s = 0; s < 2; ++s)
            #pragma unroll
            for (int r = 0; r < 4; ++r) {
                const int i = row_base + s * 16 + quad * 4 + r;
                se_p[(size_t)J * n + i]  = se[s][r];
                sp_p[(size_t)J * n + i]  = sp[s][r];
                cnt_p[(size_t)J * n + i] = cnt[s][r];
            }
    }

    // ---- col partials: cross-wave sum of the 4 LDS slots, write [I][cols] ----
    __syncthreads();
    if (I != J && tid < 128) {
        const float s0 = colred[0][0][tid] + colred[0][1][tid] + colred[0][2][tid] + colred[0][3][tid];
        const float s1 = colred[1][0][tid] + colred[1][1][tid] + colred[1][2][tid] + colred[1][3][tid];
        const float s2 = colred[2][0][tid] + colred[2][1][tid] + colred[2][2][tid] + colred[2][3][tid];
        const int j = J * 128 + tid;
        se_p[(size_t)I * n + j]  = s0;
        sp_p[(size_t)I * n + j]  = s1;
        cnt_p[(size_t)I * n + j] = s2;
    }
}

// ------- kernel 3: per-row finalize + grid reduction (last-block pattern) -------
__global__ __launch_bounds__(256) void k3_finalize(
    const float* __restrict__ diag, const float* __restrict__ se_p,
    const float* __restrict__ sp_p, const float* __restrict__ cnt_p,
    float* __restrict__ acc, unsigned* __restrict__ counter,
    float* __restrict__ out, int n)
{
    const int row = blockIdx.x * 256 + threadIdx.x;
    const int nt  = n >> 7;
    float se = 0.f, sp = 0.f, cnt = 0.f;
    for (int K = 0; K < nt; ++K) {
        se  += se_p[(size_t)K * n + row];
        sp  += sp_p[(size_t)K * n + row];
        cnt += cnt_p[(size_t)K * n + row];
    }
    const float s_ii = diag[row];
    se  -= __builtin_amdgcn_exp2f(__builtin_fmaf(s_ii, C1, -C1));
    sp  -= s_ii;
    cnt -= 1.0f;
    float loss = INVT + __logf(se) - (sp * INVT) / fmaxf(cnt, 1.0f);

    // block reduce
    #pragma unroll
    for (int m = 32; m >= 1; m >>= 1) loss += __shfl_xor(loss, m, 64);
    __shared__ float wsum[4];
    if ((threadIdx.x & 63) == 0) wsum[threadIdx.x >> 6] = loss;
    __syncthreads();
    if (threadIdx.x == 0) {
        const float bs = wsum[0] + wsum[1] + wsum[2] + wsum[3];
        atomicAdd(acc, bs);
        __threadfence();
        const unsigned old = atomicAdd(counter, 1u);
        if (old == gridDim.x - 1) {
            const float total = atomicAdd(acc, 0.0f);  // atomic load, same-address order
            out[0] = total / (float)n;
        }
    }
}

extern "C" void kernel_launch(void* const* d_in, const int* in_sizes, int n_in,
                              void* d_out, int out_size, void* d_ws, size_t ws_size,
                              hipStream_t stream) {
    const float* feat = (const float*)d_in[0];
    const float* lab  = (const float*)d_in[1];
    const int n = in_sizes[1];              // 8192
    float* out = (float*)d_out;
    const int nt = n >> 7;                  // 64 row-tiles

    // ws: fn (n*D bf16 = 2MB) | diag | se_p | sp_p | cnt_p (each nt*n f32 = 2MB) | acc | counter
    char* ws = (char*)d_ws;
    bf16* fn = (bf16*)ws;
    size_t off = (size_t)n * D * sizeof(bf16);
    float* diag  = (float*)(ws + off); off += (size_t)n * sizeof(float);
    float* se_p  = (float*)(ws + off); off += (size_t)nt * n * sizeof(float);
    float* sp_p  = (float*)(ws + off); off += (size_t)nt * n * sizeof(float);
    float* cnt_p = (float*)(ws + off); off += (size_t)nt * n * sizeof(float);
    float* acc   = (float*)(ws + off); off += sizeof(float);
    unsigned* counter = (unsigned*)(ws + off);

    k1_normalize<<<n / 4, 256, 0, stream>>>(feat, fn, diag, acc, counter, n);
    const int npairs = nt * (nt + 1) / 2;   // 2080
    k2_sym<<<npairs, 256, 0, stream>>>(fn, lab, se_p, sp_p, cnt_p, n);
    k3_finalize<<<n / 256, 256, 0, stream>>>(diag, se_p, sp_p, cnt_p, acc, counter, out, n);
}

// Round 9
// 100.551 us; speedup vs baseline: 1.6442x; 1.1126x over previous
//
#include <hip/hip_runtime.h>
#include <hip/hip_bf16.h>

using bf16 = __hip_bfloat16;
typedef __attribute__((ext_vector_type(8))) short frag_ab;   // 8 bf16
typedef __attribute__((ext_vector_type(4))) float frag_cd;   // 4 fp32

constexpr float TEMP   = 0.07f;
constexpr float INVT   = 1.0f / TEMP;                 // fixed logsumexp shift
constexpr float THRESH = 0.1f;
constexpr float EPS    = 1e-8f;
constexpr float LOG2E  = 1.4426950408889634f;
constexpr float C1     = LOG2E / TEMP;                // exp((s-1)/T) = exp2(s*C1 - C1)

constexpr int D = 128;

__device__ __forceinline__ frag_cd mfma16(frag_ab a, frag_ab b, frag_cd c) {
    return __builtin_amdgcn_mfma_f32_16x16x32_bf16(a, b, c, 0, 0, 0);
}

// ------- kernel 1: row-normalize -> bf16, diagonal dot, zero-init reduction cells -------
__global__ __launch_bounds__(256) void k1_normalize(
    const float* __restrict__ f, bf16* __restrict__ fn,
    float* __restrict__ diag, float* __restrict__ acc,
    unsigned* __restrict__ counter, int n)
{
    if (blockIdx.x == 0 && threadIdx.x == 0) { acc[0] = 0.f; counter[0] = 0u; }
    const int row  = blockIdx.x * 4 + (threadIdx.x >> 6);
    const int lane = threadIdx.x & 63;
    float2 v = ((const float2*)(f + (size_t)row * D))[lane];
    float ss = v.x * v.x + v.y * v.y;
    #pragma unroll
    for (int m = 32; m >= 1; m >>= 1) ss += __shfl_xor(ss, m, 64);
    const float inv = 1.0f / fmaxf(sqrtf(ss), EPS);
    __hip_bfloat162 o;
    o.x = __float2bfloat16(v.x * inv);
    o.y = __float2bfloat16(v.y * inv);
    ((__hip_bfloat162*)(fn + (size_t)row * D))[lane] = o;
    // diagonal raw dot of the bf16-rounded row (matches MFMA s_ii to ~1e-6)
    const float a = __bfloat162float(o.x), b = __bfloat162float(o.y);
    float p = a * a + b * b;
    #pragma unroll
    for (int m = 32; m >= 1; m >>= 1) p += __shfl_xor(p, m, 64);
    if (lane == 0) diag[row] = p;
}

// ---------------- kernel 2: symmetric fused sim + masked reductions ----------------
// One block per upper-triangle tile-pair (I<=J), 128x128; each element serves row i
// AND col j (sim/e/mask symmetric) -> half the MFMA/LDS/exp of the full sweep.
// REGISTER-PRESSURE HISTORY: full unroll of the 8-sub loop spills (R6: 208 MB,
// R7: 154 MB scratch); #pragma unroll 1 fixes spill but serializes each sub's
// ds_read(120cyc) -> mfma-chain -> epilogue, landing at ~44 us (R8). THIS REV:
// manual 2-stage pipeline over sub PAIRS with explicit double-buffered b-frags —
// next sub's ds_reads issue before current sub's epilogue; live set ~130 < 170 cap.
// Partials: float4 part[row][K] = {se,sp,cnt,pad}; block (I,J) writes rows ->
// [i][J], cols -> [j][I]; exactly one writer per cell, no atomics, no zero-init.
__global__ __launch_bounds__(256, 3) void k2_sym(
    const bf16* __restrict__ fn, const float* __restrict__ lab,
    float4* __restrict__ part, int n)
{
    __shared__ bf16  colbuf[128 * D];      // 32 KB, XOR-swizzled (0 conflicts, R4+)
    __shared__ float lab_c[128];
    __shared__ float colred[3][4][128];    // 6 KB cross-wave col-reduction scratch

    const int tid  = threadIdx.x;
    const int wave = tid >> 6;
    const int lane = tid & 63;
    const int quad = lane >> 4;
    const int l15  = lane & 15;
    const int nt   = n >> 7;               // 64 tiles

    // decode upper-triangle pair (I,J) from linear block id
    int t = blockIdx.x, I = 0;
    while (t >= nt - I) { t -= nt - I; ++I; }
    const int J = I + t;

    if (tid < 128) lab_c[tid] = lab[J * 128 + tid];

    const int row_base = I * 128 + wave * 32;

    // A fragments: set s covers rows row_base + s*16 + l15, k = kb*32 + quad*8 + j
    frag_ab afr[2][4];
    #pragma unroll
    for (int s = 0; s < 2; ++s) {
        const bf16* ap = fn + (size_t)(row_base + s * 16 + l15) * D + quad * 8;
        #pragma unroll
        for (int kb = 0; kb < 4; ++kb) afr[s][kb] = *(const frag_ab*)(ap + kb * 32);
    }
    float li[2][4];
    #pragma unroll
    for (int s = 0; s < 2; ++s)
        #pragma unroll
        for (int r = 0; r < 4; ++r)
            li[s][r] = lab[row_base + s * 16 + quad * 4 + r];

    // stage B tile (J*128 .. +128 cols x 128 k), two rounds of 4 to cap live regs
    const int c0    = tid >> 4;   // 0..15
    const int chunk = tid & 15;
    #pragma unroll
    for (int half = 0; half < 2; ++half) {
        frag_ab st[4];
        #pragma unroll
        for (int cc = 0; cc < 4; ++cc) {
            const int col = (half * 4 + cc) * 16 + c0;
            st[cc] = *(const frag_ab*)(fn + (size_t)(J * 128 + col) * D + chunk * 8);
        }
        #pragma unroll
        for (int cc = 0; cc < 4; ++cc) {
            const int col = (half * 4 + cc) * 16 + c0;
            *(frag_ab*)(&colbuf[(size_t)col * D + ((chunk ^ c0) * 8)]) = st[cc];
        }
    }
    __syncthreads();

    float se[2][4] = {}, sp[2][4] = {}, cnt[2][4] = {};

    auto loadB = [&](frag_ab (&b)[4], int sub) {
        const int c = sub * 16 + l15;
        #pragma unroll
        for (int kb = 0; kb < 4; ++kb)
            b[kb] = *(const frag_ab*)(&colbuf[(size_t)c * D + (((quad + 4 * kb) ^ l15) * 8)]);
    };
    auto body = [&](int sub, frag_ab (&b)[4]) {
        const int c = sub * 16 + l15;
        frag_cd a0 = {0.f, 0.f, 0.f, 0.f}, a1 = {0.f, 0.f, 0.f, 0.f};
        #pragma unroll
        for (int kb = 0; kb < 4; ++kb) {
            a0 = mfma16(afr[0][kb], b[kb], a0);
            a1 = mfma16(afr[1][kb], b[kb], a1);
        }
        const float lj = lab_c[c];
        float sec = 0.f, spc = 0.f, cnc = 0.f;   // this sub's col partials (transient)
        #pragma unroll
        for (int s = 0; s < 2; ++s) {
            const frag_cd& acc = s ? a1 : a0;
            #pragma unroll
            for (int r = 0; r < 4; ++r) {
                const float sv = acc[r];                      // raw dot (cosine)
                const float e  = __builtin_amdgcn_exp2f(__builtin_fmaf(sv, C1, -C1));
                const float pm = (fabsf(li[s][r] - lj) < THRESH) ? 1.0f : 0.0f;
                se[s][r]  += e;                               // row accums (registers)
                sp[s][r]   = __builtin_fmaf(pm, sv, sp[s][r]);
                cnt[s][r] += pm;
                sec += e;                                     // col accums (transient)
                spc  = __builtin_fmaf(pm, sv, spc);
                cnc += pm;
            }
        }
        // quad-reduce (sums the wave's 32 rows) then straight to LDS
        sec += __shfl_xor(sec, 16, 64); sec += __shfl_xor(sec, 32, 64);
        spc += __shfl_xor(spc, 16, 64); spc += __shfl_xor(spc, 32, 64);
        cnc += __shfl_xor(cnc, 16, 64); cnc += __shfl_xor(cnc, 32, 64);
        if (lane < 16) {
            colred[0][wave][c] = sec;
            colred[1][wave][c] = spc;
            colred[2][wave][c] = cnc;
        }
    };

    // 2-stage pipeline over sub pairs; unroll 1 keeps live set at 2 b-buffers
    frag_ab bA[4], bB[4];
    loadB(bA, 0);
    #pragma unroll 1
    for (int spr = 0; spr < 4; ++spr) {
        loadB(bB, 2 * spr + 1);        // prefetch odd sub while computing even
        body(2 * spr, bA);
        if (spr < 3) loadB(bA, 2 * spr + 2);  // prefetch next even while computing odd
        body(2 * spr + 1, bB);
    }

    // ---- row partials: reduce across the 16 lanes of each quad-group, write [i][J] ----
    #pragma unroll
    for (int s = 0; s < 2; ++s)
        #pragma unroll
        for (int r = 0; r < 4; ++r) {
            #pragma unroll
            for (int m = 1; m < 16; m <<= 1) {
                se[s][r]  += __shfl_xor(se[s][r],  m, 64);
                sp[s][r]  += __shfl_xor(sp[s][r],  m, 64);
                cnt[s][r] += __shfl_xor(cnt[s][r], m, 64);
            }
        }
    if (l15 == 0) {
        #pragma unroll
        for (int s = 0; s < 2; ++s)
            #pragma unroll
            for (int r = 0; r < 4; ++r) {
                const int i = row_base + s * 16 + quad * 4 + r;
                part[(size_t)i * nt + J] = make_float4(se[s][r], sp[s][r], cnt[s][r], 0.f);
            }
    }

    // ---- col partials: cross-wave sum of the 4 LDS slots, write [j][I] ----
    __syncthreads();
    if (I != J && tid < 128) {
        const float s0 = colred[0][0][tid] + colred[0][1][tid] + colred[0][2][tid] + colred[0][3][tid];
        const float s1 = colred[1][0][tid] + colred[1][1][tid] + colred[1][2][tid] + colred[1][3][tid];
        const float s2 = colred[2][0][tid] + colred[2][1][tid] + colred[2][2][tid] + colred[2][3][tid];
        const int j = J * 128 + tid;
        part[(size_t)j * nt + I] = make_float4(s0, s1, s2, 0.f);
    }
}

// ------- kernel 3: per-row finalize + grid reduction (last-block pattern) -------
__global__ __launch_bounds__(256) void k3_finalize(
    const float* __restrict__ diag, const float4* __restrict__ part,
    float* __restrict__ acc, unsigned* __restrict__ counter,
    float* __restrict__ out, int n)
{
    const int row = blockIdx.x * 256 + threadIdx.x;
    const int nt  = n >> 7;
    const float4* p = part + (size_t)row * nt;
    float se = 0.f, sp = 0.f, cnt = 0.f;
    #pragma unroll 8
    for (int K = 0; K < nt; ++K) {
        const float4 v = p[K];
        se += v.x; sp += v.y; cnt += v.z;
    }
    const float s_ii = diag[row];
    se  -= __builtin_amdgcn_exp2f(__builtin_fmaf(s_ii, C1, -C1));
    sp  -= s_ii;
    cnt -= 1.0f;
    float loss = INVT + __logf(se) - (sp * INVT) / fmaxf(cnt, 1.0f);

    // block reduce
    #pragma unroll
    for (int m = 32; m >= 1; m >>= 1) loss += __shfl_xor(loss, m, 64);
    __shared__ float wsum[4];
    if ((threadIdx.x & 63) == 0) wsum[threadIdx.x >> 6] = loss;
    __syncthreads();
    if (threadIdx.x == 0) {
        const float bs = wsum[0] + wsum[1] + wsum[2] + wsum[3];
        atomicAdd(acc, bs);
        __threadfence();
        const unsigned old = atomicAdd(counter, 1u);
        if (old == gridDim.x - 1) {
            const float total = atomicAdd(acc, 0.0f);  // atomic load, same-address order
            out[0] = total / (float)n;
        }
    }
}

extern "C" void kernel_launch(void* const* d_in, const int* in_sizes, int n_in,
                              void* d_out, int out_size, void* d_ws, size_t ws_size,
                              hipStream_t stream) {
    const float* feat = (const float*)d_in[0];
    const float* lab  = (const float*)d_in[1];
    const int n = in_sizes[1];              // 8192
    float* out = (float*)d_out;
    const int nt = n >> 7;                  // 64 row-tiles

    // ws: fn (n*D bf16 = 2MB) | diag (32KB) | part (n*nt float4 = 8MB) | acc | counter
    char* ws = (char*)d_ws;
    bf16* fn = (bf16*)ws;
    size_t off = (size_t)n * D * sizeof(bf16);
    float*  diag = (float*)(ws + off); off += (size_t)n * sizeof(float);
    float4* part = (float4*)(ws + off); off += (size_t)n * nt * sizeof(float4);
    float*  acc  = (float*)(ws + off); off += sizeof(float);
    unsigned* counter = (unsigned*)(ws + off);

    k1_normalize<<<n / 4, 256, 0, stream>>>(feat, fn, diag, acc, counter, n);
    const int npairs = nt * (nt + 1) / 2;   // 2080
    k2_sym<<<npairs, 256, 0, stream>>>(fn, lab, part, n);
    k3_finalize<<<n / 256, 256, 0, stream>>>(diag, part, acc, counter, out, n);
}